// Round 1
// baseline (577.226 us; speedup 1.0000x reference)
//
#include <hip/hip_runtime.h>

// Problem constants
#define NROWS    4096
#define NBR      64
#define NODE_DIM 172
#define EDGE_DIM 172
#define TIME_DIM 100
#define OUT_DIM  272
#define KEY_DIM  444          // NODE+EDGE+TIME
#define KPAD     448          // KEY_DIM padded to 32-multiple, row stride 896B (7*128 -> swizzle-closed)
#define QK_PAD   320          // OUT_DIM padded; row stride 640B (5*128 -> swizzle-closed)
#define N_HEADS  8
#define HEAD_DIM 34
#define KLDS_STRIDE 274       // odd-dword row stride for K tile -> conflict-free column reads

typedef __attribute__((ext_vector_type(8))) short short8_t;  // 8 bf16 in 4 VGPRs
typedef __attribute__((ext_vector_type(4))) float f32x4;

__device__ inline short f2b(float x) {          // fp32 -> bf16 (RNE)
  unsigned u = __builtin_bit_cast(unsigned, x);
  unsigned r = (u + 0x7fffu + ((u >> 16) & 1u)) >> 16;
  return (short)r;
}
__device__ inline float b2f(short s) {
  unsigned u = ((unsigned)(unsigned short)s) << 16;
  return __builtin_bit_cast(float, u);
}

// Stage 64 rows x D fp32 (contiguous) into XOR-swizzled bf16 LDS tile, row stride KP elems.
// Swizzle: byte_col ^= (row&7)<<4 ; valid because 2*KP is a multiple of 128.
template<int D, int KP>
__device__ inline void stage_rows(const float* __restrict__ src, int k0, char* A, int t) {
  constexpr int R4 = D / 4;
  const float4* s4 = (const float4*)src;
  for (int i = t; i < 64 * R4; i += 512) {
    float4 v = s4[i];
    int r = i / R4;
    int c = k0 + (i - r * R4) * 4;
    short4 h;
    h.x = f2b(v.x); h.y = f2b(v.y); h.z = f2b(v.z); h.w = f2b(v.w);
    *(short4*)(A + r * (2 * KP) + ((2 * c) ^ ((r & 7) << 4))) = h;
  }
}

template<int KP, int K0>
__device__ inline void pad_rows(char* A, int t) {  // zero cols K0..KP-1
  constexpr int NC = (KP - K0) / 4;
  short4 z; z.x = 0; z.y = 0; z.z = 0; z.w = 0;
  for (int i = t; i < 64 * NC; i += 512) {
    int r = i / NC;
    int c = K0 + (i - r * NC) * 4;
    *(short4*)(A + r * (2 * KP) + ((2 * c) ^ ((r & 7) << 4))) = z;
  }
}

// One 64(M) x 16(N) output stripe: acc[mt] over 4 M-tiles. B read straight from global (L2-hot),
// A from swizzled LDS. D-frag: col=lane&15, row=(lane>>4)*4+e  (m89-verified layout).
template<int KP, int NKK>
__device__ inline void gemm_tile(const short* __restrict__ Wrow, const char* A,
                                 int lr, int lk, f32x4 acc[4]) {
#pragma unroll
  for (int kk = 0; kk < NKK; ++kk) {
    short8_t bfrag = *(const short8_t*)(Wrow + lr * KP + kk * 32 + lk * 8);
#pragma unroll
    for (int mt = 0; mt < 4; ++mt) {
      short8_t afrag = *(const short8_t*)(A + (mt * 16 + lr) * (2 * KP) +
                                          ((kk * 64 + lk * 16) ^ ((lr & 7) << 4)));
      acc[mt] = __builtin_amdgcn_mfma_f32_16x16x32_bf16(afrag, bfrag, acc[mt], 0, 0, 0);
    }
  }
}

// ---------------- kernel 0: weight conversion fp32 -> padded bf16 ----------------
__global__ void convert_w(const float* __restrict__ Wkv, const float* __restrict__ Wq,
                          const float* __restrict__ Wo, short* __restrict__ wkv_b,
                          short* __restrict__ wq_b, short* __restrict__ wo_b) {
  int i = blockIdx.x * 256 + threadIdx.x;
  if (i < 544 * KPAD) {
    int r = i / KPAD, c = i - r * KPAD;
    wkv_b[i] = (c < KEY_DIM) ? f2b(Wkv[r * KEY_DIM + c]) : (short)0;
  }
  if (i < OUT_DIM * QK_PAD) {
    int r = i / QK_PAD, c = i - r * QK_PAD;
    wq_b[i] = (c < OUT_DIM) ? f2b(Wq[r * OUT_DIM + c]) : (short)0;
    wo_b[i] = (c < OUT_DIM) ? f2b(Wo[r * OUT_DIM + c]) : (short)0;
  }
}

// ---------------- kernel 1: Q = R @ W_Q^T  (64 rows per block) ----------------
__global__ __launch_bounds__(512) void q_gemm(const float* __restrict__ node_feat,
                                              const float* __restrict__ time_feat,
                                              const short* __restrict__ Wq,
                                              float* __restrict__ Qg) {
  __shared__ char Alds[64 * QK_PAD * 2];
  int rb = blockIdx.x * 64;
  int t = threadIdx.x;
  stage_rows<NODE_DIM, QK_PAD>(node_feat + (size_t)rb * NODE_DIM, 0, Alds, t);
  stage_rows<TIME_DIM, QK_PAD>(time_feat + (size_t)rb * TIME_DIM, NODE_DIM, Alds, t);
  pad_rows<QK_PAD, OUT_DIM>(Alds, t);
  __syncthreads();
  int wave = t >> 6, lane = t & 63, lr = lane & 15, lk = lane >> 4;
  f32x4 z = {0.f, 0.f, 0.f, 0.f};
  for (int nt = wave; nt < 17; nt += 8) {
    int nb = nt * 16;
    f32x4 acc[4] = {z, z, z, z};
    gemm_tile<QK_PAD, QK_PAD / 32>(Wq + nb * QK_PAD, Alds, lr, lk, acc);
#pragma unroll
    for (int mt = 0; mt < 4; ++mt)
#pragma unroll
      for (int e = 0; e < 4; ++e)
        Qg[(size_t)(rb + mt * 16 + lk * 4 + e) * OUT_DIM + nb + lr] = acc[mt][e];
  }
}

// ---------------- kernel 2: fused KV-GEMM + masked softmax attention ----------------
__global__ __launch_bounds__(512) void attn_kernel(const float* __restrict__ nbr_node,
                                                   const float* __restrict__ edge_feat,
                                                   const float* __restrict__ nbr_time,
                                                   const int* __restrict__ nbr_mask,
                                                   const short* __restrict__ Wkv,
                                                   const float* __restrict__ Qg,
                                                   float* __restrict__ Og) {
  __shared__ char Alds[64 * KPAD * 2];              // 57,344 B  (Z_in bf16, swizzled)
  __shared__ short Klds[64 * KLDS_STRIDE];          // 35,072 B
  __shared__ float Qs[OUT_DIM];
  __shared__ float P[N_HEADS * 64];
  int b = blockIdx.x;
  int t = threadIdx.x;

  stage_rows<NODE_DIM, KPAD>(nbr_node + (size_t)b * NBR * NODE_DIM, 0, Alds, t);
  stage_rows<EDGE_DIM, KPAD>(edge_feat + (size_t)b * NBR * EDGE_DIM, NODE_DIM, Alds, t);
  stage_rows<TIME_DIM, KPAD>(nbr_time + (size_t)b * NBR * TIME_DIM, NODE_DIM + EDGE_DIM, Alds, t);
  pad_rows<KPAD, KEY_DIM>(Alds, t);
  if (t < OUT_DIM) Qs[t] = Qg[(size_t)b * OUT_DIM + t];
  __syncthreads();

  int wave = t >> 6, lane = t & 63, lr = lane & 15, lk = lane >> 4;
  f32x4 z = {0.f, 0.f, 0.f, 0.f};

  // K half: Z columns [0,272)
  for (int nt = wave; nt < 17; nt += 8) {
    int nb = nt * 16;
    f32x4 acc[4] = {z, z, z, z};
    gemm_tile<KPAD, KPAD / 32>(Wkv + nb * KPAD, Alds, lr, lk, acc);
#pragma unroll
    for (int mt = 0; mt < 4; ++mt)
#pragma unroll
      for (int e = 0; e < 4; ++e)
        Klds[(mt * 16 + lk * 4 + e) * KLDS_STRIDE + nb + lr] = f2b(acc[mt][e]);
  }
  __syncthreads();

  // scores + softmax: wave w owns head w, lane l owns neighbor l
  {
    int h = wave, n = lane;
    const short* kr = &Klds[n * KLDS_STRIDE + h * HEAD_DIM];
    const float* qh = &Qs[h * HEAD_DIM];
    float s = 0.f;
#pragma unroll
    for (int d = 0; d < HEAD_DIM; ++d) s += b2f(kr[d]) * qh[d];
    s *= 0.17149858514250882f;                       // 34^-0.5
    if (nbr_mask[(size_t)b * NBR + n] == 0) s = -1e10f;
    float m = s;
#pragma unroll
    for (int off = 32; off >= 1; off >>= 1) m = fmaxf(m, __shfl_xor(m, off));
    float e = __expf(s - m);
    float sum = e;
#pragma unroll
    for (int off = 32; off >= 1; off >>= 1) sum += __shfl_xor(sum, off);
    P[h * 64 + n] = e / sum;
  }
  __syncthreads();

  // V half: Z columns [272,544) with on-the-fly O = P @ V
  for (int nt = wave; nt < 17; nt += 8) {
    int vb = nt * 16;
    f32x4 acc[4] = {z, z, z, z};
    gemm_tile<KPAD, KPAD / 32>(Wkv + (OUT_DIM + vb) * KPAD, Alds, lr, lk, acc);
    int c = vb + lr;                  // output dim, fixed per lane
    const float* Ph = &P[(c / HEAD_DIM) * 64];
    float partial = 0.f;
#pragma unroll
    for (int mt = 0; mt < 4; ++mt)
#pragma unroll
      for (int e2 = 0; e2 < 4; ++e2)
        partial += Ph[mt * 16 + lk * 4 + e2] * acc[mt][e2];
    partial += __shfl_xor(partial, 16);
    partial += __shfl_xor(partial, 32);
    if (lane < 16) Og[(size_t)b * OUT_DIM + c] = partial;
  }
}

// ---------------- kernel 3: out = LN(O @ W_O^T + b_O + R) ----------------
__global__ __launch_bounds__(512) void out_ln(const float* __restrict__ Og,
                                              const short* __restrict__ Wo,
                                              const float* __restrict__ bO,
                                              const float* __restrict__ node_feat,
                                              const float* __restrict__ time_feat,
                                              const float* __restrict__ gamma,
                                              const float* __restrict__ beta,
                                              float* __restrict__ out) {
  __shared__ char Alds[64 * QK_PAD * 2];   // 40,960 B
  __shared__ float X[64 * 276];            // 70,656 B  (x = proj + bias + residual)
  int rb = blockIdx.x * 64;
  int t = threadIdx.x;
  stage_rows<OUT_DIM, QK_PAD>(Og + (size_t)rb * OUT_DIM, 0, Alds, t);
  pad_rows<QK_PAD, OUT_DIM>(Alds, t);
  __syncthreads();
  int wave = t >> 6, lane = t & 63, lr = lane & 15, lk = lane >> 4;
  f32x4 z = {0.f, 0.f, 0.f, 0.f};
  for (int nt = wave; nt < 17; nt += 8) {
    int nb = nt * 16;
    f32x4 acc[4] = {z, z, z, z};
    gemm_tile<QK_PAD, QK_PAD / 32>(Wo + nb * QK_PAD, Alds, lr, lk, acc);
    int c = nb + lr;
    float bo = bO[c];
#pragma unroll
    for (int mt = 0; mt < 4; ++mt)
#pragma unroll
      for (int e = 0; e < 4; ++e) {
        int r = mt * 16 + lk * 4 + e;
        int gr = rb + r;
        float Rv = (c < NODE_DIM) ? node_feat[(size_t)gr * NODE_DIM + c]
                                  : time_feat[(size_t)gr * TIME_DIM + (c - NODE_DIM)];
        X[r * 276 + c] = acc[mt][e] + bo + Rv;
      }
  }
  __syncthreads();
  int row = t >> 3, j = t & 7;            // 8 lanes per row
  float s1 = 0.f, s2 = 0.f;
  for (int c = j; c < OUT_DIM; c += 8) {
    float v = X[row * 276 + c];
    s1 += v; s2 += v * v;
  }
#pragma unroll
  for (int off = 4; off >= 1; off >>= 1) {
    s1 += __shfl_xor(s1, off);
    s2 += __shfl_xor(s2, off);
  }
  float mu = s1 * (1.f / OUT_DIM);
  float var = s2 * (1.f / OUT_DIM) - mu * mu;
  float inv = rsqrtf(fmaxf(var, 0.f) + 1e-5f);
  int gr = rb + row;
  for (int c = j; c < OUT_DIM; c += 8) {
    float v = X[row * 276 + c];
    out[(size_t)gr * OUT_DIM + c] = (v - mu) * inv * gamma[c] + beta[c];
  }
}

extern "C" void kernel_launch(void* const* d_in, const int* in_sizes, int n_in,
                              void* d_out, int out_size, void* d_ws, size_t ws_size,
                              hipStream_t stream) {
  const float* node_feat = (const float*)d_in[0];
  const float* time_feat = (const float*)d_in[1];
  const float* edge_feat = (const float*)d_in[2];
  const float* nbr_node  = (const float*)d_in[3];
  const float* nbr_time  = (const float*)d_in[4];
  const int*   nbr_mask  = (const int*)d_in[5];
  const float* W_Q   = (const float*)d_in[6];
  const float* W_KV  = (const float*)d_in[7];
  const float* W_O   = (const float*)d_in[8];
  const float* b_O   = (const float*)d_in[9];
  const float* gamma = (const float*)d_in[10];
  const float* beta  = (const float*)d_in[11];

  // ws layout (needs ~9.3 MB):
  char* ws = (char*)d_ws;
  short* wkv_b = (short*)(ws);                    // 544*448*2   = 487,424
  short* wq_b  = (short*)(ws + 487424);           // 272*320*2   = 174,080
  short* wo_b  = (short*)(ws + 661504);           // 272*320*2   = 174,080
  float* Qg    = (float*)(ws + 835584);           // 4096*272*4  = 4,456,448
  float* Og    = (float*)(ws + 5292032);          // 4096*272*4  = 4,456,448 (ends 9,748,480)
  float* out   = (float*)d_out;

  convert_w<<<(544 * KPAD + 255) / 256, 256, 0, stream>>>(W_KV, W_Q, W_O, wkv_b, wq_b, wo_b);
  q_gemm<<<NROWS / 64, 512, 0, stream>>>(node_feat, time_feat, wq_b, Qg);
  attn_kernel<<<NROWS, 512, 0, stream>>>(nbr_node, edge_feat, nbr_time, nbr_mask, wkv_b, Qg, Og);
  out_ln<<<NROWS / 64, 512, 0, stream>>>(Og, wo_b, b_O, node_feat, time_feat, gamma, beta, out);
}